// Round 2
// baseline (324.971 us; speedup 1.0000x reference)
//
#include <hip/hip_runtime.h>
#include <math.h>

#define NTOK 16384
#define DDIM 512
#define MDIM 1024
#define NEXP 8
#define BKW 64       // K-step in shorts; LDS row = 128 bytes
#define TMAX 264     // max row-tiles across experts: 256 + 8 partial

typedef __attribute__((ext_vector_type(8))) short short8;
typedef __attribute__((ext_vector_type(4))) float floatx4;

__device__ inline unsigned short f2bf(float f){
  union { float f; unsigned int u; } v; v.f = f;
  unsigned int u = v.u;
  u += ((u >> 16) & 1u) + 0x7fffu;   // round-to-nearest-even
  return (unsigned short)(u >> 16);
}

__device__ inline float bf2f(unsigned short s){
  union { unsigned int u; float f; } v;
  v.u = ((unsigned int)s) << 16;
  return v.f;
}

// branch-free erf-based gelu, A&S 7.1.26 (|erf err| <= 1.5e-7)
__device__ inline float gelu_fast(float x){
  float u = x * 0.70710678118654752f;
  float a = fabsf(u);
  float t = __builtin_amdgcn_rcpf(fmaf(0.3275911f, a, 1.0f));
  float p = fmaf(1.061405429f, t, -1.453152027f);
  p = fmaf(p, t, 1.421413741f);
  p = fmaf(p, t, -0.284496736f);
  p = fmaf(p, t, 0.254829592f);
  p = p * t;
  float e = __expf(-u * u);
  float erfa = fmaf(-p, e, 1.0f);         // erf(|u|)
  float erfu = copysignf(erfa, u);
  return 0.5f * x * (1.0f + erfu);
}

// async global -> LDS, 16 bytes per lane; lds base must be wave-uniform
__device__ __forceinline__ void gload16(const unsigned short* g, unsigned short* l){
  __builtin_amdgcn_global_load_lds(
      (const __attribute__((address_space(1))) void*)g,
      (__attribute__((address_space(3))) void*)l,
      16, 0, 0);
}

// ---------------- small setup kernels ----------------

__global__ void init_small_kernel(int* counts, float* imp){
  int t = threadIdx.x;
  if (t < NEXP){ counts[t] = 0; imp[t] = 0.0f; }
}

// out[e][c][r] = bf16(in[e][r][c]); per-expert matrix is R x C
__global__ void transpose_conv_kernel(const float* __restrict__ in,
                                      unsigned short* __restrict__ out,
                                      int R, int C){
  __shared__ float tile[32][33];
  int e  = blockIdx.z;
  int c0 = blockIdx.x << 5;
  int r0 = blockIdx.y << 5;
  const float* src = in + (size_t)e * R * C;
  unsigned short* dst = out + (size_t)e * R * C;
  int tc = threadIdx.x;   // 0..31
  int tr = threadIdx.y;   // 0..7
  #pragma unroll
  for (int i = 0; i < 32; i += 8)
    tile[tr + i][tc] = src[(size_t)(r0 + tr + i) * C + c0 + tc];
  __syncthreads();
  #pragma unroll
  for (int i = 0; i < 32; i += 8)
    dst[(size_t)(c0 + tr + i) * R + r0 + tc] = f2bf(tile[tc][tr + i]);
}

// ---------------- fused gating + x->bf16 conversion ----------------

__global__ __launch_bounds__(256)
void gating_kernel(const float* __restrict__ x,
                   const float* __restrict__ wg,
                   unsigned short* __restrict__ xb,
                   int* __restrict__ tok_e, float* __restrict__ tok_g,
                   int* __restrict__ counts, float* __restrict__ imp){
  __shared__ int   lcnt[NEXP];
  __shared__ float limp[NEXP];
  int t = threadIdx.x;
  if (t < NEXP){ lcnt[t] = 0; limp[t] = 0.0f; }
  __syncthreads();

  int wave = t >> 6;
  int lane = t & 63;

  for (int it = 0; it < 4; it++){
    int n = blockIdx.x * 16 + it * 4 + wave;

    const float4* xp = (const float4*)(x + (size_t)n * DDIM + lane * 8);
    float4 a = xp[0], b = xp[1];
    float xv[8] = {a.x, a.y, a.z, a.w, b.x, b.y, b.z, b.w};

    short8 xo;
    #pragma unroll
    for (int j = 0; j < 8; j++) xo[j] = (short)f2bf(xv[j]);
    *(short8*)(xb + (size_t)n * DDIM + lane * 8) = xo;

    double acc[NEXP];
    #pragma unroll
    for (int e = 0; e < NEXP; e++) acc[e] = 0.0;
    #pragma unroll
    for (int j = 0; j < 8; j++){
      const float* wr = wg + (size_t)(lane * 8 + j) * NEXP;
      #pragma unroll
      for (int e = 0; e < NEXP; e++) acc[e] += (double)xv[j] * (double)wr[e];
    }
    #pragma unroll
    for (int off = 32; off >= 1; off >>= 1){
      #pragma unroll
      for (int e = 0; e < NEXP; e++) acc[e] += __shfl_xor(acc[e], off);
    }
    if (lane == 0){
      int i0 = -1, i1 = -1;
      double l0 = -1e300, l1 = -1e300;
      #pragma unroll
      for (int e = 0; e < NEXP; e++){
        double v = acc[e];
        if (v > l0){ l1 = l0; i1 = i0; l0 = v; i0 = e; }
        else if (v > l1){ l1 = v; i1 = e; }
      }
      float ex = expf((float)(l1 - l0));
      float g0 = 1.0f / (1.0f + ex);
      float g1 = ex / (1.0f + ex);
      tok_e[n * 2]     = i0; tok_e[n * 2 + 1] = i1;
      tok_g[n * 2]     = g0; tok_g[n * 2 + 1] = g1;
      atomicAdd(&lcnt[i0], 1); atomicAdd(&lcnt[i1], 1);
      atomicAdd(&limp[i0], g0); atomicAdd(&limp[i1], g1);
    }
  }
  __syncthreads();
  if (t < NEXP){
    atomicAdd(&counts[t], lcnt[t]);
    atomicAdd(&imp[t], limp[t]);
  }
}

__global__ void loss_scan_kernel(const int* __restrict__ counts,
                                 const float* __restrict__ imp,
                                 int* __restrict__ offsets, int* __restrict__ cursor,
                                 int* __restrict__ tile_pre,
                                 float* __restrict__ out_loss){
  int off = 0, tp = 0;
  double si = 0, si2 = 0, sl = 0, sl2 = 0;
  for (int e = 0; e < NEXP; e++){
    offsets[e] = off; cursor[e] = off;
    tile_pre[e] = tp;
    tp += (counts[e] + 127) >> 7;
    off += counts[e];
    double im = (double)imp[e];
    double ld = (double)counts[e];
    si += im; si2 += im * im;
    sl += ld; sl2 += ld * ld;
  }
  offsets[NEXP] = off;
  tile_pre[NEXP] = tp;
  double mi = si / 8.0, ml = sl / 8.0;
  double vi = (si2 - 8.0 * mi * mi) / 7.0;
  double vl = (sl2 - 8.0 * ml * ml) / 7.0;
  double loss = 0.01 * (vi / (mi * mi + 1e-10) + vl / (ml * ml + 1e-10));
  *out_loss = (float)loss;
}

// hierarchical scatter: LDS histogram -> 8 global atomics per block -> ranked write
__global__ __launch_bounds__(256)
void scatter_kernel(const int* __restrict__ tok_e,
                    int* __restrict__ cursor,
                    int* __restrict__ btok, int* __restrict__ slot_of){
  __shared__ int lcnt[NEXP];
  __shared__ int lbase[NEXP];
  int t = threadIdx.x;
  if (t < NEXP) lcnt[t] = 0;
  __syncthreads();

  int n = blockIdx.x * 256 + t;
  int e0 = tok_e[n * 2], e1 = tok_e[n * 2 + 1];
  int r0 = atomicAdd(&lcnt[e0], 1);
  int r1 = atomicAdd(&lcnt[e1], 1);
  __syncthreads();
  if (t < NEXP) lbase[t] = atomicAdd(&cursor[t], lcnt[t]);
  __syncthreads();
  int s0 = lbase[e0] + r0;
  int s1 = lbase[e1] + r1;
  btok[s0] = n;
  btok[s1] = n;
  slot_of[n * 2]     = s0;
  slot_of[n * 2 + 1] = s1;
}

// ---------------- expert GEMMs: 128x128 tile, BK=64, single-buffer ----------------
// LDS layout per matrix: [128 rows][64 shorts] (128B rows), 16 KB each.
// XOR chunk-swizzle (rule 21, both sides): global SOURCE chunk = c ^ (row&7) with a
// LINEAR global_load_lds dest; ds_read applies the same XOR -> 2-way banks (free).
// Balanced XCD swizzle: tt low-3-bits = b&7 so each tt's ct-group shares one XCD's
// L2 while dead/partial tiles spread evenly across XCDs.

__global__ __launch_bounds__(256)
void gemm1_kernel(const unsigned short* __restrict__ xb,
                  const unsigned short* __restrict__ w1t,   // [E][M][D]
                  const float* __restrict__ b1,             // [E][M]
                  const int* __restrict__ offsets,
                  const int* __restrict__ tile_pre,
                  const int* __restrict__ btok,
                  unsigned short* __restrict__ H){          // [slot][M]
  int b = blockIdx.x;                  // grid = 8*TMAX
  int x = b & 7;
  int u = b >> 3;                      // 0..TMAX-1
  int ct = u & 7;                      // column tile 0..7
  int tt = ((u >> 3) << 3) | x;        // row tile; low 3 bits = XCD
  if (tt >= tile_pre[NEXP]) return;
  int e = 0;
  while (tt >= tile_pre[e + 1]) e++;
  int rt = tt - tile_pre[e];
  int off = offsets[e];
  int cnt = offsets[e + 1] - off;
  int r0 = rt << 7;

  __shared__ unsigned short As[128 * BKW];
  __shared__ unsigned short Bs[128 * BKW];

  int t = threadIdx.x;
  int w = t >> 6;
  int rp = t >> 3;          // 0..31: row within a 32-row staging pass
  int cs = (t & 7) ^ (rp & 7);   // pre-swizzled source chunk (involution)

  const unsigned short* apt[4];
  const unsigned short* bpt[4];
  #pragma unroll
  for (int i = 0; i < 4; i++){
    int ra = r0 + i * 32 + rp;  if (ra >= cnt) ra = cnt - 1;
    apt[i] = xb + (size_t)btok[off + ra] * DDIM + cs * 8;
    bpt[i] = w1t + ((size_t)e * MDIM + (ct << 7) + i * 32 + rp) * DDIM + cs * 8;
  }

  int lane = t & 63;
  int wr = (w >> 1) << 6;
  int wc = (w & 1) << 6;
  int lm = lane & 15;
  int lq = lane >> 4;
  int h  = lm & 7;

  int aoff[4], boff[4];
  #pragma unroll
  for (int i = 0; i < 4; i++){
    aoff[i] = (wr + i * 16 + lm) * BKW + ((lq ^ h) << 3);
    boff[i] = (wc + i * 16 + lm) * BKW + ((lq ^ h) << 3);
  }

  floatx4 acc[4][4] = {};
  for (int k0 = 0; k0 < DDIM; k0 += BKW){
    #pragma unroll
    for (int i = 0; i < 4; i++){
      gload16(apt[i] + k0, As + i * 2048 + w * 512);
      gload16(bpt[i] + k0, Bs + i * 2048 + w * 512);
    }
    __syncthreads();
    #pragma unroll
    for (int kk = 0; kk < 2; kk++){
      short8 af[4], bfr[4];
      #pragma unroll
      for (int i = 0; i < 4; i++) af[i]  = *(const short8*)(As + (aoff[i] ^ (kk << 5)));
      #pragma unroll
      for (int j = 0; j < 4; j++) bfr[j] = *(const short8*)(Bs + (boff[j] ^ (kk << 5)));
      #pragma unroll
      for (int i = 0; i < 4; i++)
        #pragma unroll
        for (int j = 0; j < 4; j++)
          acc[i][j] = __builtin_amdgcn_mfma_f32_16x16x32_bf16(af[i], bfr[j], acc[i][j], 0, 0, 0);
    }
    __syncthreads();
  }

  const float* bias = b1 + e * MDIM + (ct << 7);
  #pragma unroll
  for (int i = 0; i < 4; i++){
    int rbase = wr + i * 16 + lq * 4;
    #pragma unroll
    for (int j = 0; j < 4; j++){
      int cc = wc + j * 16 + lm;
      float bv = bias[cc];
      #pragma unroll
      for (int r = 0; r < 4; r++){
        int row = r0 + rbase + r;
        if (row < cnt){
          float v = acc[i][j][r] + bv;
          H[(size_t)(off + row) * MDIM + (ct << 7) + cc] = f2bf(gelu_fast(v));
        }
      }
    }
  }
}

__global__ __launch_bounds__(256)
void gemm2_kernel(const unsigned short* __restrict__ H,    // [slot][M]
                  const unsigned short* __restrict__ w2t,  // [E][D][M]
                  const float* __restrict__ b2,            // [E][D]
                  const int* __restrict__ offsets,
                  const int* __restrict__ tile_pre,
                  unsigned short* __restrict__ O){         // [slot][D] bf16
  int b = blockIdx.x;                  // grid = 4*TMAX
  int x = b & 7;
  int u = b >> 3;                      // 0..TMAX/2-1
  int ct = u & 3;                      // column tile 0..3
  int tt = ((u >> 2) << 3) | x;        // row tile; low 3 bits = XCD
  if (tt >= tile_pre[NEXP]) return;
  int e = 0;
  while (tt >= tile_pre[e + 1]) e++;
  int rt = tt - tile_pre[e];
  int off = offsets[e];
  int cnt = offsets[e + 1] - off;
  int r0 = rt << 7;

  __shared__ unsigned short As[128 * BKW];
  __shared__ unsigned short Bs[128 * BKW];

  int t = threadIdx.x;
  int w = t >> 6;
  int rp = t >> 3;
  int cs = (t & 7) ^ (rp & 7);

  const unsigned short* apt[4];
  const unsigned short* bpt[4];
  #pragma unroll
  for (int i = 0; i < 4; i++){
    int ra = r0 + i * 32 + rp;  if (ra >= cnt) ra = cnt - 1;
    apt[i] = H + (size_t)(off + ra) * MDIM + cs * 8;
    bpt[i] = w2t + ((size_t)e * DDIM + (ct << 7) + i * 32 + rp) * MDIM + cs * 8;
  }

  int lane = t & 63;
  int wr = (w >> 1) << 6;
  int wc = (w & 1) << 6;
  int lm = lane & 15;
  int lq = lane >> 4;
  int h  = lm & 7;

  int aoff[4], boff[4];
  #pragma unroll
  for (int i = 0; i < 4; i++){
    aoff[i] = (wr + i * 16 + lm) * BKW + ((lq ^ h) << 3);
    boff[i] = (wc + i * 16 + lm) * BKW + ((lq ^ h) << 3);
  }

  floatx4 acc[4][4] = {};
  for (int k0 = 0; k0 < MDIM; k0 += BKW){
    #pragma unroll
    for (int i = 0; i < 4; i++){
      gload16(apt[i] + k0, As + i * 2048 + w * 512);
      gload16(bpt[i] + k0, Bs + i * 2048 + w * 512);
    }
    __syncthreads();
    #pragma unroll
    for (int kk = 0; kk < 2; kk++){
      short8 af[4], bfr[4];
      #pragma unroll
      for (int i = 0; i < 4; i++) af[i]  = *(const short8*)(As + (aoff[i] ^ (kk << 5)));
      #pragma unroll
      for (int j = 0; j < 4; j++) bfr[j] = *(const short8*)(Bs + (boff[j] ^ (kk << 5)));
      #pragma unroll
      for (int i = 0; i < 4; i++)
        #pragma unroll
        for (int j = 0; j < 4; j++)
          acc[i][j] = __builtin_amdgcn_mfma_f32_16x16x32_bf16(af[i], bfr[j], acc[i][j], 0, 0, 0);
    }
    __syncthreads();
  }

  const float* bias = b2 + e * DDIM + (ct << 7);
  #pragma unroll
  for (int i = 0; i < 4; i++){
    int rbase = wr + i * 16 + lq * 4;
    #pragma unroll
    for (int j = 0; j < 4; j++){
      int cc = wc + j * 16 + lm;
      float bv = bias[cc];
      #pragma unroll
      for (int r = 0; r < 4; r++){
        int row = r0 + rbase + r;
        if (row < cnt)
          O[(size_t)(off + row) * DDIM + (ct << 7) + cc] = f2bf(acc[i][j][r] + bv);
      }
    }
  }
}

// ---------------- gate-weighted combine: y[n] = g0*O[s0] + g1*O[s1] ----------------

__global__ __launch_bounds__(256)
void combine_kernel(const unsigned short* __restrict__ O,
                    const float* __restrict__ tok_g,
                    const int* __restrict__ slot_of,
                    float* __restrict__ y){
  int wave = threadIdx.x >> 6;
  int lane = threadIdx.x & 63;
  int n = blockIdx.x * 4 + wave;
  int s0 = slot_of[n * 2], s1 = slot_of[n * 2 + 1];
  float g0 = tok_g[n * 2], g1 = tok_g[n * 2 + 1];
  short8 a = *(const short8*)(O + (size_t)s0 * DDIM + lane * 8);
  short8 b = *(const short8*)(O + (size_t)s1 * DDIM + lane * 8);
  float4 o0, o1;
  float* po0 = (float*)&o0;
  float* po1 = (float*)&o1;
  #pragma unroll
  for (int j = 0; j < 4; j++){
    po0[j] = g0 * bf2f((unsigned short)a[j]) + g1 * bf2f((unsigned short)b[j]);
    po1[j] = g0 * bf2f((unsigned short)a[j + 4]) + g1 * bf2f((unsigned short)b[j + 4]);
  }
  float4* yp = (float4*)(y + (size_t)n * DDIM + lane * 8);
  yp[0] = o0;
  yp[1] = o1;
}

// ---------------- launch ----------------

extern "C" void kernel_launch(void* const* d_in, const int* in_sizes, int n_in,
                              void* d_out, int out_size, void* d_ws, size_t ws_size,
                              hipStream_t stream){
  const float* x  = (const float*)d_in[0];
  const float* wg = (const float*)d_in[1];
  const float* W1 = (const float*)d_in[2];
  const float* b1 = (const float*)d_in[3];
  const float* W2 = (const float*)d_in[4];
  const float* b2 = (const float*)d_in[5];
  float* y = (float*)d_out;

  char* ws = (char*)d_ws;
  size_t o = 0;
  auto alloc = [&](size_t bytes)->char*{
    char* p = ws + o;
    o += (bytes + 255) & ~(size_t)255;
    return p;
  };
  unsigned short* xb   = (unsigned short*)alloc((size_t)NTOK * DDIM * 2);
  unsigned short* w1t  = (unsigned short*)alloc((size_t)NEXP * MDIM * DDIM * 2);
  unsigned short* w2t  = (unsigned short*)alloc((size_t)NEXP * DDIM * MDIM * 2);
  unsigned short* H    = (unsigned short*)alloc((size_t)NTOK * 2 * MDIM * 2);
  unsigned short* O    = (unsigned short*)alloc((size_t)NTOK * 2 * DDIM * 2);
  int*   btok    = (int*)  alloc((size_t)NTOK * 2 * 4);
  int*   slot_of = (int*)  alloc((size_t)NTOK * 2 * 4);
  int*   tok_e   = (int*)  alloc((size_t)NTOK * 2 * 4);
  float* tok_g   = (float*)alloc((size_t)NTOK * 2 * 4);
  int*   counts  = (int*)  alloc(64);
  float* imp     = (float*)alloc(64);
  int*   offsets = (int*)  alloc(64);
  int*   cursor  = (int*)  alloc(64);
  int*   tile_pre= (int*)  alloc(64);

  hipLaunchKernelGGL(init_small_kernel, dim3(1), dim3(64), 0, stream, counts, imp);
  hipLaunchKernelGGL(transpose_conv_kernel, dim3(MDIM / 32, DDIM / 32, NEXP), dim3(32, 8), 0, stream,
                     W1, w1t, DDIM, MDIM);
  hipLaunchKernelGGL(transpose_conv_kernel, dim3(DDIM / 32, MDIM / 32, NEXP), dim3(32, 8), 0, stream,
                     W2, w2t, MDIM, DDIM);
  hipLaunchKernelGGL(gating_kernel, dim3(NTOK / 16), dim3(256), 0, stream,
                     x, wg, xb, tok_e, tok_g, counts, imp);
  hipLaunchKernelGGL(loss_scan_kernel, dim3(1), dim3(1), 0, stream,
                     counts, imp, offsets, cursor, tile_pre, y + (size_t)NTOK * DDIM);
  hipLaunchKernelGGL(scatter_kernel, dim3(NTOK / 256), dim3(256), 0, stream,
                     tok_e, cursor, btok, slot_of);
  hipLaunchKernelGGL(gemm1_kernel, dim3(TMAX * 8), dim3(256), 0, stream,
                     xb, w1t, b1, offsets, tile_pre, btok, H);
  hipLaunchKernelGGL(gemm2_kernel, dim3(TMAX * 4), dim3(256), 0, stream,
                     H, w2t, b2, offsets, tile_pre, O);
  hipLaunchKernelGGL(combine_kernel, dim3(NTOK / 4), dim3(256), 0, stream,
                     O, tok_g, slot_of, y);
}

// Round 3
// 303.081 us; speedup vs baseline: 1.0722x; 1.0722x over previous
//
#include <hip/hip_runtime.h>
#include <math.h>

#define NTOK 16384
#define DDIM 512
#define MDIM 1024
#define NEXP 8
#define BKW 32       // K-step in shorts; LDS row = 64 bytes
#define TMAX 264     // max row-tiles across experts: 256 + 8 partial

typedef __attribute__((ext_vector_type(8))) short short8;
typedef __attribute__((ext_vector_type(4))) float floatx4;

__device__ inline unsigned short f2bf(float f){
  union { float f; unsigned int u; } v; v.f = f;
  unsigned int u = v.u;
  u += ((u >> 16) & 1u) + 0x7fffu;   // round-to-nearest-even
  return (unsigned short)(u >> 16);
}

__device__ inline float bf2f(unsigned short s){
  union { unsigned int u; float f; } v;
  v.u = ((unsigned int)s) << 16;
  return v.f;
}

// branch-free erf-based gelu, A&S 7.1.26 (|erf err| <= 1.5e-7)
__device__ inline float gelu_fast(float x){
  float u = x * 0.70710678118654752f;
  float a = fabsf(u);
  float t = __builtin_amdgcn_rcpf(fmaf(0.3275911f, a, 1.0f));
  float p = fmaf(1.061405429f, t, -1.453152027f);
  p = fmaf(p, t, 1.421413741f);
  p = fmaf(p, t, -0.284496736f);
  p = fmaf(p, t, 0.254829592f);
  p = p * t;
  float e = __expf(-u * u);
  float erfa = fmaf(-p, e, 1.0f);         // erf(|u|)
  float erfu = copysignf(erfa, u);
  return 0.5f * x * (1.0f + erfu);
}

// async global -> LDS, 16 bytes per lane; lds base must be wave-uniform
__device__ __forceinline__ void gload16(const unsigned short* g, unsigned short* l){
  __builtin_amdgcn_global_load_lds(
      (const __attribute__((address_space(1))) void*)g,
      (__attribute__((address_space(3))) void*)l,
      16, 0, 0);
}

// ---------------- small setup kernels ----------------

__global__ void init_small_kernel(int* counts, float* imp){
  int t = threadIdx.x;
  if (t < NEXP){ counts[t] = 0; imp[t] = 0.0f; }
}

// out[e][c][r] = bf16(in[e][r][c]); per-expert matrix is R x C
__global__ void transpose_conv_kernel(const float* __restrict__ in,
                                      unsigned short* __restrict__ out,
                                      int R, int C){
  __shared__ float tile[32][33];
  int e  = blockIdx.z;
  int c0 = blockIdx.x << 5;
  int r0 = blockIdx.y << 5;
  const float* src = in + (size_t)e * R * C;
  unsigned short* dst = out + (size_t)e * R * C;
  int tc = threadIdx.x;   // 0..31
  int tr = threadIdx.y;   // 0..7
  #pragma unroll
  for (int i = 0; i < 32; i += 8)
    tile[tr + i][tc] = src[(size_t)(r0 + tr + i) * C + c0 + tc];
  __syncthreads();
  #pragma unroll
  for (int i = 0; i < 32; i += 8)
    dst[(size_t)(c0 + tr + i) * R + r0 + tc] = f2bf(tile[tc][tr + i]);
}

// ---------------- fused gating + x->bf16 conversion ----------------

__global__ __launch_bounds__(256)
void gating_kernel(const float* __restrict__ x,
                   const float* __restrict__ wg,
                   unsigned short* __restrict__ xb,
                   int* __restrict__ tok_e, float* __restrict__ tok_g,
                   int* __restrict__ counts, float* __restrict__ imp){
  __shared__ int   lcnt[NEXP];
  __shared__ float limp[NEXP];
  int t = threadIdx.x;
  if (t < NEXP){ lcnt[t] = 0; limp[t] = 0.0f; }
  __syncthreads();

  int wave = t >> 6;
  int lane = t & 63;

  for (int it = 0; it < 4; it++){
    int n = blockIdx.x * 16 + it * 4 + wave;

    const float4* xp = (const float4*)(x + (size_t)n * DDIM + lane * 8);
    float4 a = xp[0], b = xp[1];
    float xv[8] = {a.x, a.y, a.z, a.w, b.x, b.y, b.z, b.w};

    short8 xo;
    #pragma unroll
    for (int j = 0; j < 8; j++) xo[j] = (short)f2bf(xv[j]);
    *(short8*)(xb + (size_t)n * DDIM + lane * 8) = xo;

    double acc[NEXP];
    #pragma unroll
    for (int e = 0; e < NEXP; e++) acc[e] = 0.0;
    #pragma unroll
    for (int j = 0; j < 8; j++){
      const float* wr = wg + (size_t)(lane * 8 + j) * NEXP;
      #pragma unroll
      for (int e = 0; e < NEXP; e++) acc[e] += (double)xv[j] * (double)wr[e];
    }
    #pragma unroll
    for (int off = 32; off >= 1; off >>= 1){
      #pragma unroll
      for (int e = 0; e < NEXP; e++) acc[e] += __shfl_xor(acc[e], off);
    }
    if (lane == 0){
      int i0 = -1, i1 = -1;
      double l0 = -1e300, l1 = -1e300;
      #pragma unroll
      for (int e = 0; e < NEXP; e++){
        double v = acc[e];
        if (v > l0){ l1 = l0; i1 = i0; l0 = v; i0 = e; }
        else if (v > l1){ l1 = v; i1 = e; }
      }
      float ex = expf((float)(l1 - l0));
      float g0 = 1.0f / (1.0f + ex);
      float g1 = ex / (1.0f + ex);
      tok_e[n * 2]     = i0; tok_e[n * 2 + 1] = i1;
      tok_g[n * 2]     = g0; tok_g[n * 2 + 1] = g1;
      atomicAdd(&lcnt[i0], 1); atomicAdd(&lcnt[i1], 1);
      atomicAdd(&limp[i0], g0); atomicAdd(&limp[i1], g1);
    }
  }
  __syncthreads();
  if (t < NEXP){
    atomicAdd(&counts[t], lcnt[t]);
    atomicAdd(&imp[t], limp[t]);
  }
}

__global__ void loss_scan_kernel(const int* __restrict__ counts,
                                 const float* __restrict__ imp,
                                 int* __restrict__ offsets, int* __restrict__ cursor,
                                 int* __restrict__ tile_pre,
                                 float* __restrict__ out_loss){
  int off = 0, tp = 0;
  double si = 0, si2 = 0, sl = 0, sl2 = 0;
  for (int e = 0; e < NEXP; e++){
    offsets[e] = off; cursor[e] = off;
    tile_pre[e] = tp;
    tp += (counts[e] + 127) >> 7;
    off += counts[e];
    double im = (double)imp[e];
    double ld = (double)counts[e];
    si += im; si2 += im * im;
    sl += ld; sl2 += ld * ld;
  }
  offsets[NEXP] = off;
  tile_pre[NEXP] = tp;
  double mi = si / 8.0, ml = sl / 8.0;
  double vi = (si2 - 8.0 * mi * mi) / 7.0;
  double vl = (sl2 - 8.0 * ml * ml) / 7.0;
  double loss = 0.01 * (vi / (mi * mi + 1e-10) + vl / (ml * ml + 1e-10));
  *out_loss = (float)loss;
}

// hierarchical scatter: LDS histogram -> 8 global atomics per block -> ranked write
__global__ __launch_bounds__(256)
void scatter_kernel(const int* __restrict__ tok_e,
                    int* __restrict__ cursor,
                    int* __restrict__ btok, int* __restrict__ slot_of){
  __shared__ int lcnt[NEXP];
  __shared__ int lbase[NEXP];
  int t = threadIdx.x;
  if (t < NEXP) lcnt[t] = 0;
  __syncthreads();

  int n = blockIdx.x * 256 + t;
  int e0 = tok_e[n * 2], e1 = tok_e[n * 2 + 1];
  int r0 = atomicAdd(&lcnt[e0], 1);
  int r1 = atomicAdd(&lcnt[e1], 1);
  __syncthreads();
  if (t < NEXP) lbase[t] = atomicAdd(&cursor[t], lcnt[t]);
  __syncthreads();
  int s0 = lbase[e0] + r0;
  int s1 = lbase[e1] + r1;
  btok[s0] = n;
  btok[s1] = n;
  slot_of[n * 2]     = s0;
  slot_of[n * 2 + 1] = s1;
}

// ---------------- expert GEMMs: 128x128 tile, BK=32, double-buffered pipeline ----
// Min-2-phase recipe (T3): per K-step {STAGE(k+1 -> buf^1); COMPUTE(buf);
// s_waitcnt vmcnt(0); s_barrier}. STAGE sits after the previous barrier so all
// waves' reads of buf^1 are done (no WAR); drain happens AFTER compute so the
// load latency hides under the MFMAs. Raw s_barrier (no implicit vmcnt drain of
// the prefetch) + sched_barrier(0) fences pin the phases (rule 18).
// LDS: 2 x (A 8KB + B 8KB) = 32 KB. XOR chunk-swizzle both-sides (rule 21):
// source chunk (l&3)^((l>>3)&3) with linear DMA dest; read chunk lq^((lm>>1)&3)
// -> 2 lanes/bank-slot (free). XCD map: contiguous tt-range per XCD (round-1
// map, FETCH 30 MB) so each XCD's B working set is 1-2 experts (<4MB L2).

__global__ __launch_bounds__(256)
void gemm1_kernel(const unsigned short* __restrict__ xb,
                  const unsigned short* __restrict__ w1t,   // [E][M][D]
                  const float* __restrict__ b1,             // [E][M]
                  const int* __restrict__ offsets,
                  const int* __restrict__ tile_pre,
                  const int* __restrict__ btok,
                  unsigned short* __restrict__ H){          // [slot][M]
  int b = blockIdx.x;                  // grid = 8*TMAX
  int L = (b & 7) * TMAX + (b >> 3);   // contiguous logical chunk per XCD
  int ct = L & 7;                      // column tile 0..7
  int tt = L >> 3;                     // row tile
  if (tt >= tile_pre[NEXP]) return;
  int e = 0;
  while (tt >= tile_pre[e + 1]) e++;
  int rt = tt - tile_pre[e];
  int off = offsets[e];
  int cnt = offsets[e + 1] - off;
  int r0 = rt << 7;

  __shared__ unsigned short As[2 * 128 * BKW];
  __shared__ unsigned short Bs[2 * 128 * BKW];

  int t = threadIdx.x;
  int w = t >> 6;
  int l = t & 63;
  int lrow = l >> 2;                      // 0..15
  int g = (l & 3) ^ ((l >> 3) & 3);       // pre-swizzled source chunk

  // staging: instr i of wave w covers tile rows (i*4+w)*16 + lrow
  const unsigned short* apt0;
  const unsigned short* apt1;
  {
    int ra0 = r0 + (0 * 4 + w) * 16 + lrow; if (ra0 >= cnt) ra0 = cnt - 1;
    int ra1 = r0 + (1 * 4 + w) * 16 + lrow; if (ra1 >= cnt) ra1 = cnt - 1;
    apt0 = xb + (size_t)btok[off + ra0] * DDIM + g * 8;
    apt1 = xb + (size_t)btok[off + ra1] * DDIM + g * 8;
  }
  const unsigned short* bpt0 = w1t + ((size_t)e * MDIM + (ct << 7) + w * 16 + lrow) * DDIM + g * 8;
  const unsigned short* bpt1 = bpt0 + (size_t)64 * DDIM;

  int lane = t & 63;
  int wr = (w >> 1) << 6;
  int wc = (w & 1) << 6;
  int lm = lane & 15;
  int lq = lane >> 4;
  int swz = (lm >> 1) & 3;

  int aoff[4], boff[4];
  #pragma unroll
  for (int i = 0; i < 4; i++){
    aoff[i] = (wr + i * 16 + lm) * BKW + ((lq ^ swz) << 3);
    boff[i] = (wc + i * 16 + lm) * BKW + ((lq ^ swz) << 3);
  }

  floatx4 acc[4][4] = {};

  #define STAGE1(K0, CB) {                                   \
    unsigned short* Ac = As + ((CB) << 12);                  \
    unsigned short* Bc = Bs + ((CB) << 12);                  \
    gload16(apt0 + (K0), Ac + w * 512);                      \
    gload16(apt1 + (K0), Ac + 2048 + w * 512);               \
    gload16(bpt0 + (K0), Bc + w * 512);                      \
    gload16(bpt1 + (K0), Bc + 2048 + w * 512);               \
  }
  #define COMPUTE1(CB) {                                     \
    const unsigned short* Ac = As + ((CB) << 12);            \
    const unsigned short* Bc = Bs + ((CB) << 12);            \
    short8 af[4], bfr[4];                                    \
    _Pragma("unroll")                                        \
    for (int i = 0; i < 4; i++) af[i]  = *(const short8*)(Ac + aoff[i]); \
    _Pragma("unroll")                                        \
    for (int j = 0; j < 4; j++) bfr[j] = *(const short8*)(Bc + boff[j]); \
    _Pragma("unroll")                                        \
    for (int i = 0; i < 4; i++)                              \
      _Pragma("unroll")                                      \
      for (int j = 0; j < 4; j++)                            \
        acc[i][j] = __builtin_amdgcn_mfma_f32_16x16x32_bf16(af[i], bfr[j], acc[i][j], 0, 0, 0); \
  }

  int cur = 0;
  STAGE1(0, 0);
  asm volatile("s_waitcnt vmcnt(0)" ::: "memory");
  __builtin_amdgcn_sched_barrier(0);
  __builtin_amdgcn_s_barrier();
  __builtin_amdgcn_sched_barrier(0);
  for (int k = 1; k < DDIM / BKW; k++){
    STAGE1(k * BKW, cur ^ 1);
    COMPUTE1(cur);
    asm volatile("s_waitcnt vmcnt(0)" ::: "memory");
    __builtin_amdgcn_sched_barrier(0);
    __builtin_amdgcn_s_barrier();
    __builtin_amdgcn_sched_barrier(0);
    cur ^= 1;
  }
  COMPUTE1(cur);
  #undef STAGE1
  #undef COMPUTE1

  const float* bias = b1 + e * MDIM + (ct << 7);
  #pragma unroll
  for (int i = 0; i < 4; i++){
    int rbase = wr + i * 16 + lq * 4;
    #pragma unroll
    for (int j = 0; j < 4; j++){
      int cc = wc + j * 16 + lm;
      float bv = bias[cc];
      #pragma unroll
      for (int r = 0; r < 4; r++){
        int row = r0 + rbase + r;
        if (row < cnt){
          float v = acc[i][j][r] + bv;
          H[(size_t)(off + row) * MDIM + (ct << 7) + cc] = f2bf(gelu_fast(v));
        }
      }
    }
  }
}

__global__ __launch_bounds__(256)
void gemm2_kernel(const unsigned short* __restrict__ H,    // [slot][M]
                  const unsigned short* __restrict__ w2t,  // [E][D][M]
                  const float* __restrict__ b2,            // [E][D]
                  const int* __restrict__ offsets,
                  const int* __restrict__ tile_pre,
                  unsigned short* __restrict__ O){         // [slot][D] bf16
  int b = blockIdx.x;                        // grid = 4*TMAX = 8*(TMAX/2)
  int L = (b & 7) * (TMAX / 2) + (b >> 3);   // contiguous logical chunk per XCD
  int ct = L & 3;                            // column tile 0..3
  int tt = L >> 2;                           // row tile
  if (tt >= tile_pre[NEXP]) return;
  int e = 0;
  while (tt >= tile_pre[e + 1]) e++;
  int rt = tt - tile_pre[e];
  int off = offsets[e];
  int cnt = offsets[e + 1] - off;
  int r0 = rt << 7;

  __shared__ unsigned short As[2 * 128 * BKW];
  __shared__ unsigned short Bs[2 * 128 * BKW];

  int t = threadIdx.x;
  int w = t >> 6;
  int l = t & 63;
  int lrow = l >> 2;
  int g = (l & 3) ^ ((l >> 3) & 3);

  const unsigned short* apt0;
  const unsigned short* apt1;
  {
    int ra0 = r0 + w * 16 + lrow;        if (ra0 >= cnt) ra0 = cnt - 1;
    int ra1 = r0 + 64 + w * 16 + lrow;   if (ra1 >= cnt) ra1 = cnt - 1;
    apt0 = H + (size_t)(off + ra0) * MDIM + g * 8;
    apt1 = H + (size_t)(off + ra1) * MDIM + g * 8;
  }
  const unsigned short* bpt0 = w2t + ((size_t)e * DDIM + (ct << 7) + w * 16 + lrow) * MDIM + g * 8;
  const unsigned short* bpt1 = bpt0 + (size_t)64 * MDIM;

  int lane = t & 63;
  int wr = (w >> 1) << 6;
  int wc = (w & 1) << 6;
  int lm = lane & 15;
  int lq = lane >> 4;
  int swz = (lm >> 1) & 3;

  int aoff[4], boff[4];
  #pragma unroll
  for (int i = 0; i < 4; i++){
    aoff[i] = (wr + i * 16 + lm) * BKW + ((lq ^ swz) << 3);
    boff[i] = (wc + i * 16 + lm) * BKW + ((lq ^ swz) << 3);
  }

  floatx4 acc[4][4] = {};

  #define STAGE2(K0, CB) {                                   \
    unsigned short* Ac = As + ((CB) << 12);                  \
    unsigned short* Bc = Bs + ((CB) << 12);                  \
    gload16(apt0 + (K0), Ac + w * 512);                      \
    gload16(apt1 + (K0), Ac + 2048 + w * 512);               \
    gload16(bpt0 + (K0), Bc + w * 512);                      \
    gload16(bpt1 + (K0), Bc + 2048 + w * 512);               \
  }
  #define COMPUTE2(CB) {                                     \
    const unsigned short* Ac = As + ((CB) << 12);            \
    const unsigned short* Bc = Bs + ((CB) << 12);            \
    short8 af[4], bfr[4];                                    \
    _Pragma("unroll")                                        \
    for (int i = 0; i < 4; i++) af[i]  = *(const short8*)(Ac + aoff[i]); \
    _Pragma("unroll")                                        \
    for (int j = 0; j < 4; j++) bfr[j] = *(const short8*)(Bc + boff[j]); \
    _Pragma("unroll")                                        \
    for (int i = 0; i < 4; i++)                              \
      _Pragma("unroll")                                      \
      for (int j = 0; j < 4; j++)                            \
        acc[i][j] = __builtin_amdgcn_mfma_f32_16x16x32_bf16(af[i], bfr[j], acc[i][j], 0, 0, 0); \
  }

  int cur = 0;
  STAGE2(0, 0);
  asm volatile("s_waitcnt vmcnt(0)" ::: "memory");
  __builtin_amdgcn_sched_barrier(0);
  __builtin_amdgcn_s_barrier();
  __builtin_amdgcn_sched_barrier(0);
  for (int k = 1; k < MDIM / BKW; k++){
    STAGE2(k * BKW, cur ^ 1);
    COMPUTE2(cur);
    asm volatile("s_waitcnt vmcnt(0)" ::: "memory");
    __builtin_amdgcn_sched_barrier(0);
    __builtin_amdgcn_s_barrier();
    __builtin_amdgcn_sched_barrier(0);
    cur ^= 1;
  }
  COMPUTE2(cur);
  #undef STAGE2
  #undef COMPUTE2

  const float* bias = b2 + e * DDIM + (ct << 7);
  #pragma unroll
  for (int i = 0; i < 4; i++){
    int rbase = wr + i * 16 + lq * 4;
    #pragma unroll
    for (int j = 0; j < 4; j++){
      int cc = wc + j * 16 + lm;
      float bv = bias[cc];
      #pragma unroll
      for (int r = 0; r < 4; r++){
        int row = r0 + rbase + r;
        if (row < cnt)
          O[(size_t)(off + row) * DDIM + (ct << 7) + cc] = f2bf(acc[i][j][r] + bv);
      }
    }
  }
}

// ---------------- gate-weighted combine: y[n] = g0*O[s0] + g1*O[s1] ----------------

__global__ __launch_bounds__(256)
void combine_kernel(const unsigned short* __restrict__ O,
                    const float* __restrict__ tok_g,
                    const int* __restrict__ slot_of,
                    float* __restrict__ y){
  int wave = threadIdx.x >> 6;
  int lane = threadIdx.x & 63;
  int n = blockIdx.x * 4 + wave;
  int s0 = slot_of[n * 2], s1 = slot_of[n * 2 + 1];
  float g0 = tok_g[n * 2], g1 = tok_g[n * 2 + 1];
  short8 a = *(const short8*)(O + (size_t)s0 * DDIM + lane * 8);
  short8 b = *(const short8*)(O + (size_t)s1 * DDIM + lane * 8);
  float4 o0, o1;
  float* po0 = (float*)&o0;
  float* po1 = (float*)&o1;
  #pragma unroll
  for (int j = 0; j < 4; j++){
    po0[j] = g0 * bf2f((unsigned short)a[j]) + g1 * bf2f((unsigned short)b[j]);
    po1[j] = g0 * bf2f((unsigned short)a[j + 4]) + g1 * bf2f((unsigned short)b[j + 4]);
  }
  float4* yp = (float4*)(y + (size_t)n * DDIM + lane * 8);
  yp[0] = o0;
  yp[1] = o1;
}

// ---------------- launch ----------------

extern "C" void kernel_launch(void* const* d_in, const int* in_sizes, int n_in,
                              void* d_out, int out_size, void* d_ws, size_t ws_size,
                              hipStream_t stream){
  const float* x  = (const float*)d_in[0];
  const float* wg = (const float*)d_in[1];
  const float* W1 = (const float*)d_in[2];
  const float* b1 = (const float*)d_in[3];
  const float* W2 = (const float*)d_in[4];
  const float* b2 = (const float*)d_in[5];
  float* y = (float*)d_out;

  char* ws = (char*)d_ws;
  size_t o = 0;
  auto alloc = [&](size_t bytes)->char*{
    char* p = ws + o;
    o += (bytes + 255) & ~(size_t)255;
    return p;
  };
  unsigned short* xb   = (unsigned short*)alloc((size_t)NTOK * DDIM * 2);
  unsigned short* w1t  = (unsigned short*)alloc((size_t)NEXP * MDIM * DDIM * 2);
  unsigned short* w2t  = (unsigned short*)alloc((size_t)NEXP * DDIM * MDIM * 2);
  unsigned short* H    = (unsigned short*)alloc((size_t)NTOK * 2 * MDIM * 2);
  unsigned short* O    = (unsigned short*)alloc((size_t)NTOK * 2 * DDIM * 2);
  int*   btok    = (int*)  alloc((size_t)NTOK * 2 * 4);
  int*   slot_of = (int*)  alloc((size_t)NTOK * 2 * 4);
  int*   tok_e   = (int*)  alloc((size_t)NTOK * 2 * 4);
  float* tok_g   = (float*)alloc((size_t)NTOK * 2 * 4);
  int*   counts  = (int*)  alloc(64);
  float* imp     = (float*)alloc(64);
  int*   offsets = (int*)  alloc(64);
  int*   cursor  = (int*)  alloc(64);
  int*   tile_pre= (int*)  alloc(64);

  hipLaunchKernelGGL(init_small_kernel, dim3(1), dim3(64), 0, stream, counts, imp);
  hipLaunchKernelGGL(transpose_conv_kernel, dim3(MDIM / 32, DDIM / 32, NEXP), dim3(32, 8), 0, stream,
                     W1, w1t, DDIM, MDIM);
  hipLaunchKernelGGL(transpose_conv_kernel, dim3(DDIM / 32, MDIM / 32, NEXP), dim3(32, 8), 0, stream,
                     W2, w2t, MDIM, DDIM);
  hipLaunchKernelGGL(gating_kernel, dim3(NTOK / 16), dim3(256), 0, stream,
                     x, wg, xb, tok_e, tok_g, counts, imp);
  hipLaunchKernelGGL(loss_scan_kernel, dim3(1), dim3(1), 0, stream,
                     counts, imp, offsets, cursor, tile_pre, y + (size_t)NTOK * DDIM);
  hipLaunchKernelGGL(scatter_kernel, dim3(NTOK / 256), dim3(256), 0, stream,
                     tok_e, cursor, btok, slot_of);
  hipLaunchKernelGGL(gemm1_kernel, dim3(TMAX * 8), dim3(256), 0, stream,
                     xb, w1t, b1, offsets, tile_pre, btok, H);
  hipLaunchKernelGGL(gemm2_kernel, dim3(TMAX * 4), dim3(256), 0, stream,
                     H, w2t, b2, offsets, tile_pre, O);
  hipLaunchKernelGGL(combine_kernel, dim3(NTOK / 4), dim3(256), 0, stream,
                     O, tok_g, slot_of, y);
}

// Round 4
// 285.028 us; speedup vs baseline: 1.1401x; 1.0633x over previous
//
#include <hip/hip_runtime.h>
#include <math.h>

#define NTOK 16384
#define DDIM 512
#define MDIM 1024
#define NEXP 8
#define BKW 32       // K-step in shorts; LDS row = 64 bytes
#define TMAX 264     // max row-tiles across experts: 256 + 8 partial

typedef __attribute__((ext_vector_type(8))) short short8;
typedef __attribute__((ext_vector_type(4))) float floatx4;

__device__ inline unsigned short f2bf(float f){
  union { float f; unsigned int u; } v; v.f = f;
  unsigned int u = v.u;
  u += ((u >> 16) & 1u) + 0x7fffu;   // round-to-nearest-even
  return (unsigned short)(u >> 16);
}

__device__ inline float bf2f(unsigned short s){
  union { unsigned int u; float f; } v;
  v.u = ((unsigned int)s) << 16;
  return v.f;
}

// branch-free erf-based gelu, A&S 7.1.26 (|erf err| <= 1.5e-7)
__device__ inline float gelu_fast(float x){
  float u = x * 0.70710678118654752f;
  float a = fabsf(u);
  float t = __builtin_amdgcn_rcpf(fmaf(0.3275911f, a, 1.0f));
  float p = fmaf(1.061405429f, t, -1.453152027f);
  p = fmaf(p, t, 1.421413741f);
  p = fmaf(p, t, -0.284496736f);
  p = fmaf(p, t, 0.254829592f);
  p = p * t;
  float e = __expf(-u * u);
  float erfa = fmaf(-p, e, 1.0f);         // erf(|u|)
  float erfu = copysignf(erfa, u);
  return 0.5f * x * (1.0f + erfu);
}

// async global -> LDS, 16 bytes per lane; lds base must be wave-uniform
__device__ __forceinline__ void gload16(const unsigned short* g, unsigned short* l){
  __builtin_amdgcn_global_load_lds(
      (const __attribute__((address_space(1))) void*)g,
      (__attribute__((address_space(3))) void*)l,
      16, 0, 0);
}

// ---------------- small setup kernels ----------------

__global__ void init_small_kernel(int* counts, float* imp){
  int t = threadIdx.x;
  if (t < NEXP){ counts[t] = 0; imp[t] = 0.0f; }
}

// out[e][c][r] = bf16(in[e][r][c]); per-expert matrix is R x C
__global__ void transpose_conv_kernel(const float* __restrict__ in,
                                      unsigned short* __restrict__ out,
                                      int R, int C){
  __shared__ float tile[32][33];
  int e  = blockIdx.z;
  int c0 = blockIdx.x << 5;
  int r0 = blockIdx.y << 5;
  const float* src = in + (size_t)e * R * C;
  unsigned short* dst = out + (size_t)e * R * C;
  int tc = threadIdx.x;   // 0..31
  int tr = threadIdx.y;   // 0..7
  #pragma unroll
  for (int i = 0; i < 32; i += 8)
    tile[tr + i][tc] = src[(size_t)(r0 + tr + i) * C + c0 + tc];
  __syncthreads();
  #pragma unroll
  for (int i = 0; i < 32; i += 8)
    dst[(size_t)(c0 + tr + i) * R + r0 + tc] = f2bf(tile[tc][tr + i]);
}

// ---------------- fused gating + x->bf16 conversion ----------------

__global__ __launch_bounds__(256)
void gating_kernel(const float* __restrict__ x,
                   const float* __restrict__ wg,
                   unsigned short* __restrict__ xb,
                   int* __restrict__ tok_e, float* __restrict__ tok_g,
                   int* __restrict__ counts, float* __restrict__ imp){
  __shared__ int   lcnt[NEXP];
  __shared__ float limp[NEXP];
  int t = threadIdx.x;
  if (t < NEXP){ lcnt[t] = 0; limp[t] = 0.0f; }
  __syncthreads();

  int wave = t >> 6;
  int lane = t & 63;

  for (int it = 0; it < 4; it++){
    int n = blockIdx.x * 16 + it * 4 + wave;

    const float4* xp = (const float4*)(x + (size_t)n * DDIM + lane * 8);
    float4 a = xp[0], b = xp[1];
    float xv[8] = {a.x, a.y, a.z, a.w, b.x, b.y, b.z, b.w};

    short8 xo;
    #pragma unroll
    for (int j = 0; j < 8; j++) xo[j] = (short)f2bf(xv[j]);
    *(short8*)(xb + (size_t)n * DDIM + lane * 8) = xo;

    double acc[NEXP];
    #pragma unroll
    for (int e = 0; e < NEXP; e++) acc[e] = 0.0;
    #pragma unroll
    for (int j = 0; j < 8; j++){
      const float* wr = wg + (size_t)(lane * 8 + j) * NEXP;
      #pragma unroll
      for (int e = 0; e < NEXP; e++) acc[e] += (double)xv[j] * (double)wr[e];
    }
    #pragma unroll
    for (int off = 32; off >= 1; off >>= 1){
      #pragma unroll
      for (int e = 0; e < NEXP; e++) acc[e] += __shfl_xor(acc[e], off);
    }
    if (lane == 0){
      int i0 = -1, i1 = -1;
      double l0 = -1e300, l1 = -1e300;
      #pragma unroll
      for (int e = 0; e < NEXP; e++){
        double v = acc[e];
        if (v > l0){ l1 = l0; i1 = i0; l0 = v; i0 = e; }
        else if (v > l1){ l1 = v; i1 = e; }
      }
      float ex = expf((float)(l1 - l0));
      float g0 = 1.0f / (1.0f + ex);
      float g1 = ex / (1.0f + ex);
      tok_e[n * 2]     = i0; tok_e[n * 2 + 1] = i1;
      tok_g[n * 2]     = g0; tok_g[n * 2 + 1] = g1;
      atomicAdd(&lcnt[i0], 1); atomicAdd(&lcnt[i1], 1);
      atomicAdd(&limp[i0], g0); atomicAdd(&limp[i1], g1);
    }
  }
  __syncthreads();
  if (t < NEXP){
    atomicAdd(&counts[t], lcnt[t]);
    atomicAdd(&imp[t], limp[t]);
  }
}

__global__ void loss_scan_kernel(const int* __restrict__ counts,
                                 const float* __restrict__ imp,
                                 int* __restrict__ offsets, int* __restrict__ cursor,
                                 int* __restrict__ tile_pre,
                                 float* __restrict__ out_loss){
  int off = 0, tp = 0;
  double si = 0, si2 = 0, sl = 0, sl2 = 0;
  for (int e = 0; e < NEXP; e++){
    offsets[e] = off; cursor[e] = off;
    tile_pre[e] = tp;
    tp += (counts[e] + 127) >> 7;
    off += counts[e];
    double im = (double)imp[e];
    double ld = (double)counts[e];
    si += im; si2 += im * im;
    sl += ld; sl2 += ld * ld;
  }
  offsets[NEXP] = off;
  tile_pre[NEXP] = tp;
  double mi = si / 8.0, ml = sl / 8.0;
  double vi = (si2 - 8.0 * mi * mi) / 7.0;
  double vl = (sl2 - 8.0 * ml * ml) / 7.0;
  double loss = 0.01 * (vi / (mi * mi + 1e-10) + vl / (ml * ml + 1e-10));
  *out_loss = (float)loss;
}

// hierarchical scatter: LDS histogram -> 8 global atomics per block -> ranked write
__global__ __launch_bounds__(256)
void scatter_kernel(const int* __restrict__ tok_e,
                    int* __restrict__ cursor,
                    int* __restrict__ btok, int* __restrict__ slot_of){
  __shared__ int lcnt[NEXP];
  __shared__ int lbase[NEXP];
  int t = threadIdx.x;
  if (t < NEXP) lcnt[t] = 0;
  __syncthreads();

  int n = blockIdx.x * 256 + t;
  int e0 = tok_e[n * 2], e1 = tok_e[n * 2 + 1];
  int r0 = atomicAdd(&lcnt[e0], 1);
  int r1 = atomicAdd(&lcnt[e1], 1);
  __syncthreads();
  if (t < NEXP) lbase[t] = atomicAdd(&cursor[t], lcnt[t]);
  __syncthreads();
  int s0 = lbase[e0] + r0;
  int s1 = lbase[e1] + r1;
  btok[s0] = n;
  btok[s1] = n;
  slot_of[n * 2]     = s0;
  slot_of[n * 2 + 1] = s1;
}

// ------- expert GEMMs: 128x128 tile, BK=32, depth-2 counted-vmcnt pipeline -------
// T4 (counted vmcnt): 3 LDS buffers; prologue stages steps 0,1; step k does
//   {ds_read frags(buf k%3); STAGE(k+2 -> buf (k+2)%3); MFMA; vmcnt(4); s_barrier}
// vmcnt(4) retires only STAGE(k+1) (oldest 4 loads); STAGE(k+2)'s 4 loads stay in
// flight ACROSS the barrier -> each STAGE gets ~2 full steps to fly (drain-to-0 at
// rounds 0-3 gave it ~0-1 step and all landed 82-109us).
// RAW: end-of-step-(k-1) vmcnt(4)+barrier => all waves' STAGE(k) complete.
// WAR: STAGE(k+2) overwrites buf[(k-1)%3]; barrier k-1 => its ds_reads consumed.
// Tail peeled: step NK-2 waits vmcnt(0); step NK-1 computes, no barrier.
// XOR chunk-swizzle both-sides (rule 21) and contiguous-tt XCD map kept from r3.

__global__ __launch_bounds__(256)
void gemm1_kernel(const unsigned short* __restrict__ xb,
                  const unsigned short* __restrict__ w1t,   // [E][M][D]
                  const float* __restrict__ b1,             // [E][M]
                  const int* __restrict__ offsets,
                  const int* __restrict__ tile_pre,
                  const int* __restrict__ btok,
                  unsigned short* __restrict__ H){          // [slot][M]
  int b = blockIdx.x;                  // grid = 8*TMAX
  int L = (b & 7) * TMAX + (b >> 3);   // contiguous logical chunk per XCD
  int ct = L & 7;                      // column tile 0..7
  int tt = L >> 3;                     // row tile
  if (tt >= tile_pre[NEXP]) return;
  int e = 0;
  while (tt >= tile_pre[e + 1]) e++;
  int rt = tt - tile_pre[e];
  int off = offsets[e];
  int cnt = offsets[e + 1] - off;
  int r0 = rt << 7;

  __shared__ unsigned short As[3 * 128 * BKW];
  __shared__ unsigned short Bs[3 * 128 * BKW];

  int t = threadIdx.x;
  int w = t >> 6;
  int l = t & 63;
  int lrow = l >> 2;                      // 0..15
  int g = (l & 3) ^ ((l >> 3) & 3);       // pre-swizzled source chunk

  const unsigned short* apt0;
  const unsigned short* apt1;
  {
    int ra0 = r0 + w * 16 + lrow;        if (ra0 >= cnt) ra0 = cnt - 1;
    int ra1 = r0 + 64 + w * 16 + lrow;   if (ra1 >= cnt) ra1 = cnt - 1;
    apt0 = xb + (size_t)btok[off + ra0] * DDIM + g * 8;
    apt1 = xb + (size_t)btok[off + ra1] * DDIM + g * 8;
  }
  const unsigned short* bpt0 = w1t + ((size_t)e * MDIM + (ct << 7) + w * 16 + lrow) * DDIM + g * 8;
  const unsigned short* bpt1 = bpt0 + (size_t)64 * DDIM;

  int lane = t & 63;
  int wr = (w >> 1) << 6;
  int wc = (w & 1) << 6;
  int lm = lane & 15;
  int lq = lane >> 4;
  int swz = (lm >> 1) & 3;

  int aoff[4], boff[4];
  #pragma unroll
  for (int i = 0; i < 4; i++){
    aoff[i] = (wr + i * 16 + lm) * BKW + ((lq ^ swz) << 3);
    boff[i] = (wc + i * 16 + lm) * BKW + ((lq ^ swz) << 3);
  }

  floatx4 acc[4][4] = {};

  #define STAGE1(K0, CB) {                                   \
    unsigned short* Ac = As + (CB) * 4096;                   \
    unsigned short* Bc = Bs + (CB) * 4096;                   \
    gload16(apt0 + (K0), Ac + w * 512);                      \
    gload16(apt1 + (K0), Ac + 2048 + w * 512);               \
    gload16(bpt0 + (K0), Bc + w * 512);                      \
    gload16(bpt1 + (K0), Bc + 2048 + w * 512);               \
  }
  #define READ1(CB) {                                        \
    const unsigned short* Ac = As + (CB) * 4096;             \
    const unsigned short* Bc = Bs + (CB) * 4096;             \
    _Pragma("unroll")                                        \
    for (int i = 0; i < 4; i++) af[i]  = *(const short8*)(Ac + aoff[i]); \
    _Pragma("unroll")                                        \
    for (int j = 0; j < 4; j++) bfr[j] = *(const short8*)(Bc + boff[j]); \
  }
  #define MFMA1 {                                            \
    _Pragma("unroll")                                        \
    for (int i = 0; i < 4; i++)                              \
      _Pragma("unroll")                                      \
      for (int j = 0; j < 4; j++)                            \
        acc[i][j] = __builtin_amdgcn_mfma_f32_16x16x32_bf16(af[i], bfr[j], acc[i][j], 0, 0, 0); \
  }
  #define WAITBAR(N) {                                       \
    asm volatile("s_waitcnt vmcnt(" #N ")" ::: "memory");    \
    __builtin_amdgcn_sched_barrier(0);                       \
    __builtin_amdgcn_s_barrier();                            \
    __builtin_amdgcn_sched_barrier(0);                       \
  }

  const int NK = DDIM / BKW;             // 16
  STAGE1(0, 0);
  STAGE1(BKW, 1);
  WAITBAR(4);                            // buf0 ready; STAGE(1) in flight
  int cur = 0;
  for (int k = 0; k < NK - 2; k++){
    int st = cur + 2; if (st >= 3) st -= 3;
    short8 af[4], bfr[4];
    READ1(cur);
    STAGE1((k + 2) * BKW, st);
    MFMA1;
    WAITBAR(4);                          // retire STAGE(k+1); STAGE(k+2) stays out
    cur = (cur + 1 == 3) ? 0 : cur + 1;
  }
  {                                      // step NK-2: only STAGE(NK-1) outstanding
    short8 af[4], bfr[4];
    READ1(cur);
    MFMA1;
    WAITBAR(0);
    cur = (cur + 1 == 3) ? 0 : cur + 1;
  }
  {                                      // step NK-1: no barrier after
    short8 af[4], bfr[4];
    READ1(cur);
    MFMA1;
  }
  #undef STAGE1
  #undef READ1
  #undef MFMA1
  #undef WAITBAR

  const float* bias = b1 + e * MDIM + (ct << 7);
  #pragma unroll
  for (int i = 0; i < 4; i++){
    int rbase = wr + i * 16 + lq * 4;
    #pragma unroll
    for (int j = 0; j < 4; j++){
      int cc = wc + j * 16 + lm;
      float bv = bias[cc];
      #pragma unroll
      for (int r = 0; r < 4; r++){
        int row = r0 + rbase + r;
        if (row < cnt){
          float v = acc[i][j][r] + bv;
          H[(size_t)(off + row) * MDIM + (ct << 7) + cc] = f2bf(gelu_fast(v));
        }
      }
    }
  }
}

__global__ __launch_bounds__(256)
void gemm2_kernel(const unsigned short* __restrict__ H,    // [slot][M]
                  const unsigned short* __restrict__ w2t,  // [E][D][M]
                  const float* __restrict__ b2,            // [E][D]
                  const int* __restrict__ offsets,
                  const int* __restrict__ tile_pre,
                  unsigned short* __restrict__ O){         // [slot][D] bf16
  int b = blockIdx.x;                        // grid = 4*TMAX = 8*(TMAX/2)
  int L = (b & 7) * (TMAX / 2) + (b >> 3);   // contiguous logical chunk per XCD
  int ct = L & 3;                            // column tile 0..3
  int tt = L >> 2;                           // row tile
  if (tt >= tile_pre[NEXP]) return;
  int e = 0;
  while (tt >= tile_pre[e + 1]) e++;
  int rt = tt - tile_pre[e];
  int off = offsets[e];
  int cnt = offsets[e + 1] - off;
  int r0 = rt << 7;

  __shared__ unsigned short As[3 * 128 * BKW];
  __shared__ unsigned short Bs[3 * 128 * BKW];

  int t = threadIdx.x;
  int w = t >> 6;
  int l = t & 63;
  int lrow = l >> 2;
  int g = (l & 3) ^ ((l >> 3) & 3);

  const unsigned short* apt0;
  const unsigned short* apt1;
  {
    int ra0 = r0 + w * 16 + lrow;        if (ra0 >= cnt) ra0 = cnt - 1;
    int ra1 = r0 + 64 + w * 16 + lrow;   if (ra1 >= cnt) ra1 = cnt - 1;
    apt0 = H + (size_t)(off + ra0) * MDIM + g * 8;
    apt1 = H + (size_t)(off + ra1) * MDIM + g * 8;
  }
  const unsigned short* bpt0 = w2t + ((size_t)e * DDIM + (ct << 7) + w * 16 + lrow) * MDIM + g * 8;
  const unsigned short* bpt1 = bpt0 + (size_t)64 * MDIM;

  int lane = t & 63;
  int wr = (w >> 1) << 6;
  int wc = (w & 1) << 6;
  int lm = lane & 15;
  int lq = lane >> 4;
  int swz = (lm >> 1) & 3;

  int aoff[4], boff[4];
  #pragma unroll
  for (int i = 0; i < 4; i++){
    aoff[i] = (wr + i * 16 + lm) * BKW + ((lq ^ swz) << 3);
    boff[i] = (wc + i * 16 + lm) * BKW + ((lq ^ swz) << 3);
  }

  floatx4 acc[4][4] = {};

  #define STAGE2(K0, CB) {                                   \
    unsigned short* Ac = As + (CB) * 4096;                   \
    unsigned short* Bc = Bs + (CB) * 4096;                   \
    gload16(apt0 + (K0), Ac + w * 512);                      \
    gload16(apt1 + (K0), Ac + 2048 + w * 512);               \
    gload16(bpt0 + (K0), Bc + w * 512);                      \
    gload16(bpt1 + (K0), Bc + 2048 + w * 512);               \
  }
  #define READ2(CB) {                                        \
    const unsigned short* Ac = As + (CB) * 4096;             \
    const unsigned short* Bc = Bs + (CB) * 4096;             \
    _Pragma("unroll")                                        \
    for (int i = 0; i < 4; i++) af[i]  = *(const short8*)(Ac + aoff[i]); \
    _Pragma("unroll")                                        \
    for (int j = 0; j < 4; j++) bfr[j] = *(const short8*)(Bc + boff[j]); \
  }
  #define MFMA2 {                                            \
    _Pragma("unroll")                                        \
    for (int i = 0; i < 4; i++)                              \
      _Pragma("unroll")                                      \
      for (int j = 0; j < 4; j++)                            \
        acc[i][j] = __builtin_amdgcn_mfma_f32_16x16x32_bf16(af[i], bfr[j], acc[i][j], 0, 0, 0); \
  }
  #define WAITBAR2(N) {                                      \
    asm volatile("s_waitcnt vmcnt(" #N ")" ::: "memory");    \
    __builtin_amdgcn_sched_barrier(0);                       \
    __builtin_amdgcn_s_barrier();                            \
    __builtin_amdgcn_sched_barrier(0);                       \
  }

  const int NK = MDIM / BKW;             // 32
  STAGE2(0, 0);
  STAGE2(BKW, 1);
  WAITBAR2(4);
  int cur = 0;
  for (int k = 0; k < NK - 2; k++){
    int st = cur + 2; if (st >= 3) st -= 3;
    short8 af[4], bfr[4];
    READ2(cur);
    STAGE2((k + 2) * BKW, st);
    MFMA2;
    WAITBAR2(4);
    cur = (cur + 1 == 3) ? 0 : cur + 1;
  }
  {
    short8 af[4], bfr[4];
    READ2(cur);
    MFMA2;
    WAITBAR2(0);
    cur = (cur + 1 == 3) ? 0 : cur + 1;
  }
  {
    short8 af[4], bfr[4];
    READ2(cur);
    MFMA2;
  }
  #undef STAGE2
  #undef READ2
  #undef MFMA2
  #undef WAITBAR2

  const float* bias = b2 + e * DDIM + (ct << 7);
  #pragma unroll
  for (int i = 0; i < 4; i++){
    int rbase = wr + i * 16 + lq * 4;
    #pragma unroll
    for (int j = 0; j < 4; j++){
      int cc = wc + j * 16 + lm;
      float bv = bias[cc];
      #pragma unroll
      for (int r = 0; r < 4; r++){
        int row = r0 + rbase + r;
        if (row < cnt)
          O[(size_t)(off + row) * DDIM + (ct << 7) + cc] = f2bf(acc[i][j][r] + bv);
      }
    }
  }
}

// ---------------- gate-weighted combine: y[n] = g0*O[s0] + g1*O[s1] ----------------

__global__ __launch_bounds__(256)
void combine_kernel(const unsigned short* __restrict__ O,
                    const float* __restrict__ tok_g,
                    const int* __restrict__ slot_of,
                    float* __restrict__ y){
  int wave = threadIdx.x >> 6;
  int lane = threadIdx.x & 63;
  int n = blockIdx.x * 4 + wave;
  int s0 = slot_of[n * 2], s1 = slot_of[n * 2 + 1];
  float g0 = tok_g[n * 2], g1 = tok_g[n * 2 + 1];
  short8 a = *(const short8*)(O + (size_t)s0 * DDIM + lane * 8);
  short8 b = *(const short8*)(O + (size_t)s1 * DDIM + lane * 8);
  float4 o0, o1;
  float* po0 = (float*)&o0;
  float* po1 = (float*)&o1;
  #pragma unroll
  for (int j = 0; j < 4; j++){
    po0[j] = g0 * bf2f((unsigned short)a[j]) + g1 * bf2f((unsigned short)b[j]);
    po1[j] = g0 * bf2f((unsigned short)a[j + 4]) + g1 * bf2f((unsigned short)b[j + 4]);
  }
  float4* yp = (float4*)(y + (size_t)n * DDIM + lane * 8);
  yp[0] = o0;
  yp[1] = o1;
}

// ---------------- launch ----------------

extern "C" void kernel_launch(void* const* d_in, const int* in_sizes, int n_in,
                              void* d_out, int out_size, void* d_ws, size_t ws_size,
                              hipStream_t stream){
  const float* x  = (const float*)d_in[0];
  const float* wg = (const float*)d_in[1];
  const float* W1 = (const float*)d_in[2];
  const float* b1 = (const float*)d_in[3];
  const float* W2 = (const float*)d_in[4];
  const float* b2 = (const float*)d_in[5];
  float* y = (float*)d_out;

  char* ws = (char*)d_ws;
  size_t o = 0;
  auto alloc = [&](size_t bytes)->char*{
    char* p = ws + o;
    o += (bytes + 255) & ~(size_t)255;
    return p;
  };
  unsigned short* xb   = (unsigned short*)alloc((size_t)NTOK * DDIM * 2);
  unsigned short* w1t  = (unsigned short*)alloc((size_t)NEXP * MDIM * DDIM * 2);
  unsigned short* w2t  = (unsigned short*)alloc((size_t)NEXP * DDIM * MDIM * 2);
  unsigned short* H    = (unsigned short*)alloc((size_t)NTOK * 2 * MDIM * 2);
  unsigned short* O    = (unsigned short*)alloc((size_t)NTOK * 2 * DDIM * 2);
  int*   btok    = (int*)  alloc((size_t)NTOK * 2 * 4);
  int*   slot_of = (int*)  alloc((size_t)NTOK * 2 * 4);
  int*   tok_e   = (int*)  alloc((size_t)NTOK * 2 * 4);
  float* tok_g   = (float*)alloc((size_t)NTOK * 2 * 4);
  int*   counts  = (int*)  alloc(64);
  float* imp     = (float*)alloc(64);
  int*   offsets = (int*)  alloc(64);
  int*   cursor  = (int*)  alloc(64);
  int*   tile_pre= (int*)  alloc(64);

  hipLaunchKernelGGL(init_small_kernel, dim3(1), dim3(64), 0, stream, counts, imp);
  hipLaunchKernelGGL(transpose_conv_kernel, dim3(MDIM / 32, DDIM / 32, NEXP), dim3(32, 8), 0, stream,
                     W1, w1t, DDIM, MDIM);
  hipLaunchKernelGGL(transpose_conv_kernel, dim3(DDIM / 32, MDIM / 32, NEXP), dim3(32, 8), 0, stream,
                     W2, w2t, MDIM, DDIM);
  hipLaunchKernelGGL(gating_kernel, dim3(NTOK / 16), dim3(256), 0, stream,
                     x, wg, xb, tok_e, tok_g, counts, imp);
  hipLaunchKernelGGL(loss_scan_kernel, dim3(1), dim3(1), 0, stream,
                     counts, imp, offsets, cursor, tile_pre, y + (size_t)NTOK * DDIM);
  hipLaunchKernelGGL(scatter_kernel, dim3(NTOK / 256), dim3(256), 0, stream,
                     tok_e, cursor, btok, slot_of);
  hipLaunchKernelGGL(gemm1_kernel, dim3(TMAX * 8), dim3(256), 0, stream,
                     xb, w1t, b1, offsets, tile_pre, btok, H);
  hipLaunchKernelGGL(gemm2_kernel, dim3(TMAX * 4), dim3(256), 0, stream,
                     H, w2t, b2, offsets, tile_pre, O);
  hipLaunchKernelGGL(combine_kernel, dim3(NTOK / 4), dim3(256), 0, stream,
                     O, tok_g, slot_of, y);
}

// Round 5
// 274.506 us; speedup vs baseline: 1.1838x; 1.0383x over previous
//
#include <hip/hip_runtime.h>
#include <math.h>

#define NTOK 16384
#define DDIM 512
#define MDIM 1024
#define NEXP 8
#define BKW 32       // K-step in shorts; LDS row = 64 bytes
#define TMAX 264     // max row-tiles across experts: 256 + 8 partial

typedef __attribute__((ext_vector_type(8))) short short8;
typedef __attribute__((ext_vector_type(4))) float floatx4;

__device__ inline unsigned short f2bf(float f){
  union { float f; unsigned int u; } v; v.f = f;
  unsigned int u = v.u;
  u += ((u >> 16) & 1u) + 0x7fffu;   // round-to-nearest-even
  return (unsigned short)(u >> 16);
}

__device__ inline float bf2f(unsigned short s){
  union { unsigned int u; float f; } v;
  v.u = ((unsigned int)s) << 16;
  return v.f;
}

// branch-free erf-based gelu, A&S 7.1.26 (|erf err| <= 1.5e-7)
__device__ inline float gelu_fast(float x){
  float u = x * 0.70710678118654752f;
  float a = fabsf(u);
  float t = __builtin_amdgcn_rcpf(fmaf(0.3275911f, a, 1.0f));
  float p = fmaf(1.061405429f, t, -1.453152027f);
  p = fmaf(p, t, 1.421413741f);
  p = fmaf(p, t, -0.284496736f);
  p = fmaf(p, t, 0.254829592f);
  p = p * t;
  float e = __expf(-u * u);
  float erfa = fmaf(-p, e, 1.0f);         // erf(|u|)
  float erfu = copysignf(erfa, u);
  return 0.5f * x * (1.0f + erfu);
}

// async global -> LDS, 16 bytes per lane; lds base must be wave-uniform
__device__ __forceinline__ void gload16(const unsigned short* g, unsigned short* l){
  __builtin_amdgcn_global_load_lds(
      (const __attribute__((address_space(1))) void*)g,
      (__attribute__((address_space(3))) void*)l,
      16, 0, 0);
}

// ---------------- small setup kernels ----------------

__global__ void init_small_kernel(int* counts, float* imp){
  int t = threadIdx.x;
  if (t < NEXP){ counts[t] = 0; imp[t] = 0.0f; }
}

// out[e][c][r] = bf16(in[e][r][c]); per-expert matrix is R x C
__global__ void transpose_conv_kernel(const float* __restrict__ in,
                                      unsigned short* __restrict__ out,
                                      int R, int C){
  __shared__ float tile[32][33];
  int e  = blockIdx.z;
  int c0 = blockIdx.x << 5;
  int r0 = blockIdx.y << 5;
  const float* src = in + (size_t)e * R * C;
  unsigned short* dst = out + (size_t)e * R * C;
  int tc = threadIdx.x;   // 0..31
  int tr = threadIdx.y;   // 0..7
  #pragma unroll
  for (int i = 0; i < 32; i += 8)
    tile[tr + i][tc] = src[(size_t)(r0 + tr + i) * C + c0 + tc];
  __syncthreads();
  #pragma unroll
  for (int i = 0; i < 32; i += 8)
    dst[(size_t)(c0 + tr + i) * R + r0 + tc] = f2bf(tile[tc][tr + i]);
}

// ---------------- fused gating + x->bf16 conversion ----------------

__global__ __launch_bounds__(256)
void gating_kernel(const float* __restrict__ x,
                   const float* __restrict__ wg,
                   unsigned short* __restrict__ xb,
                   int* __restrict__ tok_e, float* __restrict__ tok_g,
                   int* __restrict__ counts, float* __restrict__ imp){
  __shared__ int   lcnt[NEXP];
  __shared__ float limp[NEXP];
  int t = threadIdx.x;
  if (t < NEXP){ lcnt[t] = 0; limp[t] = 0.0f; }
  __syncthreads();

  int wave = t >> 6;
  int lane = t & 63;

  for (int it = 0; it < 4; it++){
    int n = blockIdx.x * 16 + it * 4 + wave;

    const float4* xp = (const float4*)(x + (size_t)n * DDIM + lane * 8);
    float4 a = xp[0], b = xp[1];
    float xv[8] = {a.x, a.y, a.z, a.w, b.x, b.y, b.z, b.w};

    short8 xo;
    #pragma unroll
    for (int j = 0; j < 8; j++) xo[j] = (short)f2bf(xv[j]);
    *(short8*)(xb + (size_t)n * DDIM + lane * 8) = xo;

    double acc[NEXP];
    #pragma unroll
    for (int e = 0; e < NEXP; e++) acc[e] = 0.0;
    #pragma unroll
    for (int j = 0; j < 8; j++){
      const float* wr = wg + (size_t)(lane * 8 + j) * NEXP;
      #pragma unroll
      for (int e = 0; e < NEXP; e++) acc[e] += (double)xv[j] * (double)wr[e];
    }
    #pragma unroll
    for (int off = 32; off >= 1; off >>= 1){
      #pragma unroll
      for (int e = 0; e < NEXP; e++) acc[e] += __shfl_xor(acc[e], off);
    }
    if (lane == 0){
      int i0 = -1, i1 = -1;
      double l0 = -1e300, l1 = -1e300;
      #pragma unroll
      for (int e = 0; e < NEXP; e++){
        double v = acc[e];
        if (v > l0){ l1 = l0; i1 = i0; l0 = v; i0 = e; }
        else if (v > l1){ l1 = v; i1 = e; }
      }
      float ex = expf((float)(l1 - l0));
      float g0 = 1.0f / (1.0f + ex);
      float g1 = ex / (1.0f + ex);
      tok_e[n * 2]     = i0; tok_e[n * 2 + 1] = i1;
      tok_g[n * 2]     = g0; tok_g[n * 2 + 1] = g1;
      atomicAdd(&lcnt[i0], 1); atomicAdd(&lcnt[i1], 1);
      atomicAdd(&limp[i0], g0); atomicAdd(&limp[i1], g1);
    }
  }
  __syncthreads();
  if (t < NEXP){
    atomicAdd(&counts[t], lcnt[t]);
    atomicAdd(&imp[t], limp[t]);
  }
}

// one-wave parallel scan (was 1-thread serial: ~50 dependent global ops)
__global__ void loss_scan_kernel(const int* __restrict__ counts,
                                 const float* __restrict__ imp,
                                 int* __restrict__ offsets, int* __restrict__ cursor,
                                 int* __restrict__ tile_pre,
                                 float* __restrict__ out_loss){
  int l = threadIdx.x;                    // 64 lanes
  int   c  = (l < NEXP) ? counts[l] : 0;
  float im = (l < NEXP) ? imp[l]    : 0.0f;
  int   tl = (c + 127) >> 7;

  int poff = 0, ptl = 0;                  // exclusive prefix over lanes 0..7
  int tot = 0, tott = 0;
  double si = 0, si2 = 0, sl = 0, sl2 = 0;
  #pragma unroll
  for (int e = 0; e < NEXP; e++){
    int   ce = __shfl(c, e);
    int   te = __shfl(tl, e);
    float ie = __shfl(im, e);
    if (e < l){ poff += ce; ptl += te; }
    tot += ce; tott += te;
    si += (double)ie; si2 += (double)ie * ie;
    sl += (double)ce; sl2 += (double)ce * ce;
  }
  if (l < NEXP){ offsets[l] = poff; cursor[l] = poff; tile_pre[l] = ptl; }
  if (l == 0){
    offsets[NEXP] = tot; tile_pre[NEXP] = tott;
    double mi = si / 8.0, ml = sl / 8.0;
    double vi = (si2 - 8.0 * mi * mi) / 7.0;
    double vl = (sl2 - 8.0 * ml * ml) / 7.0;
    *out_loss = (float)(0.01 * (vi / (mi * mi + 1e-10) + vl / (ml * ml + 1e-10)));
  }
}

// hierarchical scatter: LDS histogram -> 8 global atomics per block -> ranked write
__global__ __launch_bounds__(256)
void scatter_kernel(const int* __restrict__ tok_e,
                    int* __restrict__ cursor,
                    int* __restrict__ btok, int* __restrict__ slot_of){
  __shared__ int lcnt[NEXP];
  __shared__ int lbase[NEXP];
  int t = threadIdx.x;
  if (t < NEXP) lcnt[t] = 0;
  __syncthreads();

  int n = blockIdx.x * 256 + t;
  int e0 = tok_e[n * 2], e1 = tok_e[n * 2 + 1];
  int r0 = atomicAdd(&lcnt[e0], 1);
  int r1 = atomicAdd(&lcnt[e1], 1);
  __syncthreads();
  if (t < NEXP) lbase[t] = atomicAdd(&cursor[t], lcnt[t]);
  __syncthreads();
  int s0 = lbase[e0] + r0;
  int s1 = lbase[e1] + r1;
  btok[s0] = n;
  btok[s1] = n;
  slot_of[n * 2]     = s0;
  slot_of[n * 2 + 1] = s1;
}

// ------- expert GEMMs: 128x128 tile, 8 waves (512 thr), depth-2 counted vmcnt -------
// Same race-ledger as round 4 (passed): 3 LDS buffers; step k:
//   {ds_read frags(buf k%3); STAGE(k+2 -> buf (k+2)%3); MFMA; vmcnt(2); s_barrier}
// Now loads/STAGE = 2 (512 lanes x 16B = one 8KB matrix per gload pair) -> vmcnt(2)
// retires STAGE(k+1) while STAGE(k+2) stays in flight across the barrier.
// 8 waves/block, wave tile 32x64 (acc 2x4) -> 48KB LDS, 3 blocks/CU = 6 waves/SIMD
// (__launch_bounds__(512,6): VGPR cap 85, est. live ~76) — TLP hides step latency.
// XOR chunk-swizzle both-sides + contiguous-tt XCD map kept (FETCH 30MB, conflicts 0).

__global__ __launch_bounds__(512, 6)
void gemm1_kernel(const unsigned short* __restrict__ xb,
                  const unsigned short* __restrict__ w1t,   // [E][M][D]
                  const float* __restrict__ b1,             // [E][M]
                  const int* __restrict__ offsets,
                  const int* __restrict__ tile_pre,
                  const int* __restrict__ btok,
                  unsigned short* __restrict__ H){          // [slot][M]
  int b = blockIdx.x;                  // grid = 8*TMAX
  int L = (b & 7) * TMAX + (b >> 3);   // contiguous logical chunk per XCD
  int ct = L & 7;                      // column tile 0..7
  int tt = L >> 3;                     // row tile
  if (tt >= tile_pre[NEXP]) return;
  int e = 0;
  while (tt >= tile_pre[e + 1]) e++;
  int rt = tt - tile_pre[e];
  int off = offsets[e];
  int cnt = offsets[e + 1] - off;
  int r0 = rt << 7;

  __shared__ unsigned short As[3 * 128 * BKW];
  __shared__ unsigned short Bs[3 * 128 * BKW];

  int t = threadIdx.x;
  int w = t >> 6;                         // 0..7
  int l = t & 63;
  int g = (l & 3) ^ ((l >> 3) & 3);       // pre-swizzled source chunk

  // staging: wave w covers tile rows w*16 + (l>>2); one A-gload + one B-gload per thread
  const unsigned short* apt;
  {
    int ra = r0 + w * 16 + (l >> 2);  if (ra >= cnt) ra = cnt - 1;
    apt = xb + (size_t)btok[off + ra] * DDIM + g * 8;
  }
  const unsigned short* bpt = w1t + ((size_t)e * MDIM + (ct << 7) + w * 16 + (l >> 2)) * DDIM + g * 8;

  int wr = (w >> 1) << 5;                 // 0,32,64,96
  int wc = (w & 1) << 6;                  // 0,64
  int lm = l & 15;
  int lq = l >> 4;
  int swz = (lm >> 1) & 3;

  int aoff[2], boff[4];
  #pragma unroll
  for (int i = 0; i < 2; i++) aoff[i] = (wr + i * 16 + lm) * BKW + ((lq ^ swz) << 3);
  #pragma unroll
  for (int j = 0; j < 4; j++) boff[j] = (wc + j * 16 + lm) * BKW + ((lq ^ swz) << 3);

  floatx4 acc[2][4] = {};

  #define STAGE1(K0, CB) {                                   \
    gload16(apt + (K0), As + (CB) * 4096 + w * 512);         \
    gload16(bpt + (K0), Bs + (CB) * 4096 + w * 512);         \
  }
  #define READ1(CB) {                                        \
    const unsigned short* Ac = As + (CB) * 4096;             \
    const unsigned short* Bc = Bs + (CB) * 4096;             \
    _Pragma("unroll")                                        \
    for (int i = 0; i < 2; i++) af[i]  = *(const short8*)(Ac + aoff[i]); \
    _Pragma("unroll")                                        \
    for (int j = 0; j < 4; j++) bfr[j] = *(const short8*)(Bc + boff[j]); \
  }
  #define MFMA1 {                                            \
    _Pragma("unroll")                                        \
    for (int i = 0; i < 2; i++)                              \
      _Pragma("unroll")                                      \
      for (int j = 0; j < 4; j++)                            \
        acc[i][j] = __builtin_amdgcn_mfma_f32_16x16x32_bf16(af[i], bfr[j], acc[i][j], 0, 0, 0); \
  }
  #define WAITBAR(N) {                                       \
    asm volatile("s_waitcnt vmcnt(" #N ")" ::: "memory");    \
    __builtin_amdgcn_sched_barrier(0);                       \
    __builtin_amdgcn_s_barrier();                            \
    __builtin_amdgcn_sched_barrier(0);                       \
  }

  const int NK = DDIM / BKW;             // 16
  STAGE1(0, 0);
  STAGE1(BKW, 1);
  WAITBAR(2);                            // buf0 ready; STAGE(1) in flight
  int cur = 0;
  for (int k = 0; k < NK - 2; k++){
    int st = cur + 2; if (st >= 3) st -= 3;
    short8 af[2], bfr[4];
    READ1(cur);
    STAGE1((k + 2) * BKW, st);
    MFMA1;
    WAITBAR(2);                          // retire STAGE(k+1); STAGE(k+2) stays out
    cur = (cur + 1 == 3) ? 0 : cur + 1;
  }
  {                                      // step NK-2: only STAGE(NK-1) outstanding
    short8 af[2], bfr[4];
    READ1(cur);
    MFMA1;
    WAITBAR(0);
    cur = (cur + 1 == 3) ? 0 : cur + 1;
  }
  {                                      // step NK-1: no barrier after
    short8 af[2], bfr[4];
    READ1(cur);
    MFMA1;
  }
  #undef STAGE1
  #undef READ1
  #undef MFMA1
  #undef WAITBAR

  const float* bias = b1 + e * MDIM + (ct << 7);
  #pragma unroll
  for (int i = 0; i < 2; i++){
    int rbase = wr + i * 16 + lq * 4;
    #pragma unroll
    for (int j = 0; j < 4; j++){
      int cc = wc + j * 16 + lm;
      float bv = bias[cc];
      #pragma unroll
      for (int r = 0; r < 4; r++){
        int row = r0 + rbase + r;
        if (row < cnt){
          float v = acc[i][j][r] + bv;
          H[(size_t)(off + row) * MDIM + (ct << 7) + cc] = f2bf(gelu_fast(v));
        }
      }
    }
  }
}

__global__ __launch_bounds__(512, 6)
void gemm2_kernel(const unsigned short* __restrict__ H,    // [slot][M]
                  const unsigned short* __restrict__ w2t,  // [E][D][M]
                  const float* __restrict__ b2,            // [E][D]
                  const int* __restrict__ offsets,
                  const int* __restrict__ tile_pre,
                  unsigned short* __restrict__ O){         // [slot][D] bf16
  int b = blockIdx.x;                        // grid = 4*TMAX = 8*(TMAX/2)
  int L = (b & 7) * (TMAX / 2) + (b >> 3);   // contiguous logical chunk per XCD
  int ct = L & 3;                            // column tile 0..3
  int tt = L >> 2;                           // row tile
  if (tt >= tile_pre[NEXP]) return;
  int e = 0;
  while (tt >= tile_pre[e + 1]) e++;
  int rt = tt - tile_pre[e];
  int off = offsets[e];
  int cnt = offsets[e + 1] - off;
  int r0 = rt << 7;

  __shared__ unsigned short As[3 * 128 * BKW];
  __shared__ unsigned short Bs[3 * 128 * BKW];

  int t = threadIdx.x;
  int w = t >> 6;
  int l = t & 63;
  int g = (l & 3) ^ ((l >> 3) & 3);

  const unsigned short* apt;
  {
    int ra = r0 + w * 16 + (l >> 2);  if (ra >= cnt) ra = cnt - 1;
    apt = H + (size_t)(off + ra) * MDIM + g * 8;
  }
  const unsigned short* bpt = w2t + ((size_t)e * DDIM + (ct << 7) + w * 16 + (l >> 2)) * MDIM + g * 8;

  int wr = (w >> 1) << 5;
  int wc = (w & 1) << 6;
  int lm = l & 15;
  int lq = l >> 4;
  int swz = (lm >> 1) & 3;

  int aoff[2], boff[4];
  #pragma unroll
  for (int i = 0; i < 2; i++) aoff[i] = (wr + i * 16 + lm) * BKW + ((lq ^ swz) << 3);
  #pragma unroll
  for (int j = 0; j < 4; j++) boff[j] = (wc + j * 16 + lm) * BKW + ((lq ^ swz) << 3);

  floatx4 acc[2][4] = {};

  #define STAGE2(K0, CB) {                                   \
    gload16(apt + (K0), As + (CB) * 4096 + w * 512);         \
    gload16(bpt + (K0), Bs + (CB) * 4096 + w * 512);         \
  }
  #define READ2(CB) {                                        \
    const unsigned short* Ac = As + (CB) * 4096;             \
    const unsigned short* Bc = Bs + (CB) * 4096;             \
    _Pragma("unroll")                                        \
    for (int i = 0; i < 2; i++) af[i]  = *(const short8*)(Ac + aoff[i]); \
    _Pragma("unroll")                                        \
    for (int j = 0; j < 4; j++) bfr[j] = *(const short8*)(Bc + boff[j]); \
  }
  #define MFMA2 {                                            \
    _Pragma("unroll")                                        \
    for (int i = 0; i < 2; i++)                              \
      _Pragma("unroll")                                      \
      for (int j = 0; j < 4; j++)                            \
        acc[i][j] = __builtin_amdgcn_mfma_f32_16x16x32_bf16(af[i], bfr[j], acc[i][j], 0, 0, 0); \
  }
  #define WAITBAR2(N) {                                      \
    asm volatile("s_waitcnt vmcnt(" #N ")" ::: "memory");    \
    __builtin_amdgcn_sched_barrier(0);                       \
    __builtin_amdgcn_s_barrier();                            \
    __builtin_amdgcn_sched_barrier(0);                       \
  }

  const int NK = MDIM / BKW;             // 32
  STAGE2(0, 0);
  STAGE2(BKW, 1);
  WAITBAR2(2);
  int cur = 0;
  for (int k = 0; k < NK - 2; k++){
    int st = cur + 2; if (st >= 3) st -= 3;
    short8 af[2], bfr[4];
    READ2(cur);
    STAGE2((k + 2) * BKW, st);
    MFMA2;
    WAITBAR2(2);
    cur = (cur + 1 == 3) ? 0 : cur + 1;
  }
  {
    short8 af[2], bfr[4];
    READ2(cur);
    MFMA2;
    WAITBAR2(0);
    cur = (cur + 1 == 3) ? 0 : cur + 1;
  }
  {
    short8 af[2], bfr[4];
    READ2(cur);
    MFMA2;
  }
  #undef STAGE2
  #undef READ2
  #undef MFMA2
  #undef WAITBAR2

  const float* bias = b2 + e * DDIM + (ct << 7);
  #pragma unroll
  for (int i = 0; i < 2; i++){
    int rbase = wr + i * 16 + lq * 4;
    #pragma unroll
    for (int j = 0; j < 4; j++){
      int cc = wc + j * 16 + lm;
      float bv = bias[cc];
      #pragma unroll
      for (int r = 0; r < 4; r++){
        int row = r0 + rbase + r;
        if (row < cnt)
          O[(size_t)(off + row) * DDIM + (ct << 7) + cc] = f2bf(acc[i][j][r] + bv);
      }
    }
  }
}

// ---------------- gate-weighted combine: y[n] = g0*O[s0] + g1*O[s1] ----------------

__global__ __launch_bounds__(256)
void combine_kernel(const unsigned short* __restrict__ O,
                    const float* __restrict__ tok_g,
                    const int* __restrict__ slot_of,
                    float* __restrict__ y){
  int wave = threadIdx.x >> 6;
  int lane = threadIdx.x & 63;
  int n = blockIdx.x * 4 + wave;
  int s0 = slot_of[n * 2], s1 = slot_of[n * 2 + 1];
  float g0 = tok_g[n * 2], g1 = tok_g[n * 2 + 1];
  short8 a = *(const short8*)(O + (size_t)s0 * DDIM + lane * 8);
  short8 b = *(const short8*)(O + (size_t)s1 * DDIM + lane * 8);
  float4 o0, o1;
  float* po0 = (float*)&o0;
  float* po1 = (float*)&o1;
  #pragma unroll
  for (int j = 0; j < 4; j++){
    po0[j] = g0 * bf2f((unsigned short)a[j]) + g1 * bf2f((unsigned short)b[j]);
    po1[j] = g0 * bf2f((unsigned short)a[j + 4]) + g1 * bf2f((unsigned short)b[j + 4]);
  }
  float4* yp = (float4*)(y + (size_t)n * DDIM + lane * 8);
  yp[0] = o0;
  yp[1] = o1;
}

// ---------------- launch ----------------

extern "C" void kernel_launch(void* const* d_in, const int* in_sizes, int n_in,
                              void* d_out, int out_size, void* d_ws, size_t ws_size,
                              hipStream_t stream){
  const float* x  = (const float*)d_in[0];
  const float* wg = (const float*)d_in[1];
  const float* W1 = (const float*)d_in[2];
  const float* b1 = (const float*)d_in[3];
  const float* W2 = (const float*)d_in[4];
  const float* b2 = (const float*)d_in[5];
  float* y = (float*)d_out;

  char* ws = (char*)d_ws;
  size_t o = 0;
  auto alloc = [&](size_t bytes)->char*{
    char* p = ws + o;
    o += (bytes + 255) & ~(size_t)255;
    return p;
  };
  unsigned short* xb   = (unsigned short*)alloc((size_t)NTOK * DDIM * 2);
  unsigned short* w1t  = (unsigned short*)alloc((size_t)NEXP * MDIM * DDIM * 2);
  unsigned short* w2t  = (unsigned short*)alloc((size_t)NEXP * DDIM * MDIM * 2);
  unsigned short* H    = (unsigned short*)alloc((size_t)NTOK * 2 * MDIM * 2);
  unsigned short* O    = (unsigned short*)alloc((size_t)NTOK * 2 * DDIM * 2);
  int*   btok    = (int*)  alloc((size_t)NTOK * 2 * 4);
  int*   slot_of = (int*)  alloc((size_t)NTOK * 2 * 4);
  int*   tok_e   = (int*)  alloc((size_t)NTOK * 2 * 4);
  float* tok_g   = (float*)alloc((size_t)NTOK * 2 * 4);
  int*   counts  = (int*)  alloc(64);
  float* imp     = (float*)alloc(64);
  int*   offsets = (int*)  alloc(64);
  int*   cursor  = (int*)  alloc(64);
  int*   tile_pre= (int*)  alloc(64);

  hipLaunchKernelGGL(init_small_kernel, dim3(1), dim3(64), 0, stream, counts, imp);
  hipLaunchKernelGGL(transpose_conv_kernel, dim3(MDIM / 32, DDIM / 32, NEXP), dim3(32, 8), 0, stream,
                     W1, w1t, DDIM, MDIM);
  hipLaunchKernelGGL(transpose_conv_kernel, dim3(DDIM / 32, MDIM / 32, NEXP), dim3(32, 8), 0, stream,
                     W2, w2t, MDIM, DDIM);
  hipLaunchKernelGGL(gating_kernel, dim3(NTOK / 16), dim3(256), 0, stream,
                     x, wg, xb, tok_e, tok_g, counts, imp);
  hipLaunchKernelGGL(loss_scan_kernel, dim3(1), dim3(64), 0, stream,
                     counts, imp, offsets, cursor, tile_pre, y + (size_t)NTOK * DDIM);
  hipLaunchKernelGGL(scatter_kernel, dim3(NTOK / 256), dim3(256), 0, stream,
                     tok_e, cursor, btok, slot_of);
  hipLaunchKernelGGL(gemm1_kernel, dim3(TMAX * 8), dim3(512), 0, stream,
                     xb, w1t, b1, offsets, tile_pre, btok, H);
  hipLaunchKernelGGL(gemm2_kernel, dim3(TMAX * 4), dim3(512), 0, stream,
                     H, w2t, b2, offsets, tile_pre, O);
  hipLaunchKernelGGL(combine_kernel, dim3(NTOK / 4), dim3(256), 0, stream,
                     O, tok_g, slot_of, y);
}